// Round 4
// baseline (10185.928 us; speedup 1.0000x reference)
//
#include <hip/hip_runtime.h>

// LogEig of 32768 SPD 32x32 fp32 matrices via one-sided Jacobi.
//
// v5: v3b main loop (odd-even transposition + DPP exchange, bit-identical
// rotation sequence) with two pure-performance changes:
//  (a) 256-thread blocks = 4 independent waves = 16 matrices/block.
//      Grid = 2048 blocks = exactly 8 blocks/CU; VGPR<=64 and LDS 18.4KB
//      lift the occupancy cap from ~12 waves/CU (1-wave workgroups, 38%
//      measured) to 32 waves/CU (100%) -- hides the DPP-hazard and branch
//      bubbles that held VALUBusy at 91%.
//  (b) all v2f math expressed as __builtin_elementwise_fma with
//      pre-broadcast {cr,cr}/{sr,sr} vectors -> exact llvm.fma.v2f32 on
//      packed operands, maximizing v_pk_fma_f32/v_pk_mul_f32 selection
//      (scalar-broadcast was the likeliest scalarization trigger).
//
// v4 post-mortem (1174 us, REGRESSED vs v3b's 1120): convergence early-exit
// never fired -- near-equal eigenvalue pairs rotate freely inside their
// eigenspace, so the normalized-dot criterion stalls forever even though
// those rotations are harmless; and the o2-carry pushed VGPR 56->72,
// dropping occupancy 38->30%. Both reverted.
//
// Structure recap: per wave: 4 matrices; 16 lanes/matrix; lane `sub` owns
// columns at positions (2*sub, 2*sub+1). Even rounds rotate the lane-local
// pair (zero communication). Odd rounds pair (pos 2s+1, 2s+2): fetch
// partner with DPP row_shl:1 (lane i <- i+1), ship the updated column back
// with row_shr:1 (lane i <- i-1). Always-swap => odd-even transposition
// covers all 496 pairs exactly once per 32-round sweep. DPP rows (16 lanes)
// never cross matrix/wave boundaries. Main loop issues ZERO DS instructions.

typedef float v2f __attribute__((ext_vector_type(2)));

#define SWEEPS 10

static __device__ __forceinline__ v2f pkfma(v2f a, v2f b, v2f c) {
    return __builtin_elementwise_fma(a, b, c);
}

static __device__ __forceinline__ float dpp_next(float v) {
    // lane i <- lane i+1 within its 16-lane row (row_shl:1).
    // Row tail (lane 15) has no source -> bound_ctrl=false keeps own value.
    return __builtin_bit_cast(float, __builtin_amdgcn_update_dpp(
        __builtin_bit_cast(int, v), __builtin_bit_cast(int, v),
        0x101 /*row_shl:1*/, 0xF, 0xF, false));
}
static __device__ __forceinline__ float dpp_ship(float oldv, float srcv) {
    // lane i <- srcv from lane i-1 within its row (row_shr:1).
    // Row head (lane 0) has no source -> keeps oldv (position 0 idle).
    return __builtin_bit_cast(float, __builtin_amdgcn_update_dpp(
        __builtin_bit_cast(int, oldv), __builtin_bit_cast(int, srcv),
        0x111 /*row_shr:1*/, 0xF, 0xF, false));
}

static __device__ __forceinline__ void make_rot(float dot, float gpp, float gqq,
                                                float& cr, float& sr) {
    // Jacobi rotation zeroing Gram(p,q); small root t of t^2 + 2*tau*t - 1 = 0.
    const float tau = (gqq - gpp) * 0.5f * __builtin_amdgcn_rcpf(dot);
    const float at  = fabsf(tau);
    float t = __builtin_amdgcn_rcpf(at + __builtin_amdgcn_sqrtf(fmaf(at, at, 1.f)));
    t = copysignf(t, tau);
    if (fabsf(dot) < 1e-37f) t = 0.f;   // skip / kill 0/0 NaN
    cr = __builtin_amdgcn_rsqf(fmaf(t, t, 1.f));
    sr = t * cr;
}

__global__ __launch_bounds__(256, 8) void logeig_kernel(const float* __restrict__ P,
                                                        float* __restrict__ out,
                                                        int nmat) {
    const int tid  = threadIdx.x;     // 0..255
    const int lane = tid & 63;        // lane within wave
    const int wv   = tid >> 6;        // wave within block (0..3)
    const int sub  = lane & 15;       // lane within matrix
    const int mg   = lane >> 4;       // matrix slot within wave (0..3)
    int mat = blockIdx.x * 16 + wv * 4 + mg;
    if (mat >= nmat) mat = nmat - 1;

    // Load columns 2*sub and 2*sub+1 (P symmetric -> column == row, contiguous).
    v2f X[16], Y[16];
    {
        const float4* s4 =
            reinterpret_cast<const float4*>(P + (size_t)mat * 1024 + (size_t)sub * 64);
        #pragma unroll
        for (int k = 0; k < 8; ++k) {
            float4 v = s4[k];
            X[2*k]   = (v2f){v.x, v.y};
            X[2*k+1] = (v2f){v.z, v.w};
        }
        #pragma unroll
        for (int k = 0; k < 8; ++k) {
            float4 v = s4[8 + k];
            Y[2*k]   = (v2f){v.x, v.y};
            Y[2*k+1] = (v2f){v.z, v.w};
        }
    }

    const bool tail = (sub == 15);    // its Y = position 31: idle in odd rounds

    #pragma unroll 1
    for (int sweep = 0; sweep < SWEEPS; ++sweep) {
        #pragma unroll 1
        for (int rr = 0; rr < 16; ++rr) {
            // ---------- even round: local pair (u = X @ pos 2s, v = Y @ pos 2s+1)
            {
                v2f dA={0,0}, dB={0,0}, pA={0,0}, pB={0,0}, qA={0,0}, qB={0,0};
                #pragma unroll
                for (int k = 0; k < 16; k += 2) {
                    dA = pkfma(X[k],   Y[k],   dA);
                    pA = pkfma(X[k],   X[k],   pA);
                    qA = pkfma(Y[k],   Y[k],   qA);
                    dB = pkfma(X[k+1], Y[k+1], dB);
                    pB = pkfma(X[k+1], X[k+1], pB);
                    qB = pkfma(Y[k+1], Y[k+1], qB);
                }
                v2f dT = dA + dB, pT = pA + pB, qT = qA + qB;
                float cr, sr;
                make_rot(dT[0] + dT[1], pT[0] + pT[1], qT[0] + qT[1], cr, sr);
                const v2f crv = {cr, cr}, srv = {sr, sr}, nsv = {-sr, -sr};
                // always-swap: pos 2s <- v' = cr*Y + sr*X ; pos 2s+1 <- u' = cr*X - sr*Y
                #pragma unroll
                for (int k = 0; k < 16; ++k) {
                    const v2f xo = X[k];
                    X[k] = pkfma(crv, Y[k], srv * xo);   // cr*Y + sr*xo
                    Y[k] = pkfma(nsv, Y[k], crv * xo);   // cr*xo - sr*Y
                }
            }
            // ---------- odd round: pair (u = Y_s @ pos 2s+1, v = X_{s+1} @ pos 2s+2)
            {
                v2f dA={0,0}, dB={0,0}, pA={0,0}, pB={0,0}, qA={0,0}, qB={0,0};
                #pragma unroll
                for (int k = 0; k < 16; ++k) {
                    v2f o;
                    o[0] = dpp_next(X[k][0]);
                    o[1] = dpp_next(X[k][1]);
                    if (k & 1) { dB = pkfma(Y[k], o, dB); qB = pkfma(o, o, qB);
                                 pB = pkfma(Y[k], Y[k], pB); }
                    else       { dA = pkfma(Y[k], o, dA); qA = pkfma(o, o, qA);
                                 pA = pkfma(Y[k], Y[k], pA); }
                }
                v2f dT = dA + dB, pT = pA + pB, qT = qA + qB;
                float cr, sr;
                make_rot(dT[0] + dT[1], pT[0] + pT[1], qT[0] + qT[1], cr, sr);
                // boundary: position 31 (tail lane's Y) is unpaired -> (cr,sr)=(0,1)
                // makes Y' = Y exactly; its shipped u' dies at the row boundary.
                cr = tail ? 0.f : cr;
                sr = tail ? 1.f : sr;
                const v2f crv = {cr, cr}, srv = {sr, sr}, nsv = {-sr, -sr};
                #pragma unroll
                for (int k = 0; k < 16; ++k) {
                    v2f o;                      // refetch: X untouched until recv below
                    o[0] = dpp_next(X[k][0]);
                    o[1] = dpp_next(X[k][1]);
                    const v2f yo = Y[k];
                    Y[k] = pkfma(crv, o, srv * yo);      // v' = cr*o + sr*yo stays here
                    v2f u = pkfma(crv, yo, nsv * o);     // u' = cr*yo - sr*o ships right
                    X[k][0] = dpp_ship(X[k][0], u[0]);   // lane 0 keeps X (pos 0 idle)
                    X[k][1] = dpp_ship(X[k][1], u[1]);
                }
            }
        }
    }

    // ---------- epilogue: sigma, log, normalize; X = sum_c l_c u_c u_c^T ----------
    float nx2, ny2;
    {
        v2f a={0,0}, b={0,0};
        #pragma unroll
        for (int k = 0; k < 16; k += 2) { a = pkfma(X[k], X[k], a); b = pkfma(X[k+1], X[k+1], b); }
        v2f t = a + b; nx2 = t[0] + t[1];
    }
    {
        v2f a={0,0}, b={0,0};
        #pragma unroll
        for (int k = 0; k < 16; k += 2) { a = pkfma(Y[k], Y[k], a); b = pkfma(Y[k+1], Y[k+1], b); }
        v2f t = a + b; ny2 = t[0] + t[1];
    }
    const float invx = __builtin_amdgcn_rsqf(nx2);               // 1/sigma
    const float invy = __builtin_amdgcn_rsqf(ny2);
    const float lgx  = 0.34657359f * __builtin_amdgcn_logf(nx2); // ln(sigma)
    const float lgy  = 0.34657359f * __builtin_amdgcn_logf(ny2);

    // Per-wave LDS slice; one matrix per phase. 4 x 32 x 36 x 4B = 18432 B;
    // at 8 blocks/CU = 147 KB <= 160 KB, so LDS is not the occupancy binder.
    // Row stride 36 keeps 16-float halves 16B-aligned; log(eig) in pad [c][33].
    __shared__ __align__(16) float S[4][32][36];

    const int r = lane >> 1;       // output row this lane accumulates
    const int h = lane & 1;        // which 16-float half of that row

    #pragma unroll 1
    for (int ph = 0; ph < 4; ++ph) {
        __syncthreads();           // protect S reuse across phases (uniform count)
        if (mg == ph) {
            #pragma unroll
            for (int k = 0; k < 16; ++k) {
                *reinterpret_cast<v2f*>(&S[wv][2*sub][2*k])   = X[k] * invx;
                *reinterpret_cast<v2f*>(&S[wv][2*sub+1][2*k]) = Y[k] * invy;
            }
            S[wv][2*sub][33]   = lgx;
            S[wv][2*sub+1][33] = lgy;
        }
        __syncthreads();

        // All 64 lanes of the wave cooperate on its matrix `ph`.
        v2f acc[8];
        #pragma unroll
        for (int j = 0; j < 8; ++j) acc[j] = (v2f){0.f, 0.f};
        #pragma unroll 4
        for (int c = 0; c < 32; ++c) {
            const float m = S[wv][c][r] * S[wv][c][33];   // u_c[r] * log(lambda_c)
            const v2f mv = {m, m};
            const float4* row4 = reinterpret_cast<const float4*>(&S[wv][c][h * 16]);
            #pragma unroll
            for (int j4 = 0; j4 < 4; ++j4) {
                float4 v = row4[j4];
                acc[2*j4]   = pkfma(mv, (v2f){v.x, v.y}, acc[2*j4]);
                acc[2*j4+1] = pkfma(mv, (v2f){v.z, v.w}, acc[2*j4+1]);
            }
        }
        int m2 = blockIdx.x * 16 + wv * 4 + ph;
        if (m2 >= nmat) m2 = nmat - 1;
        // lane -> (r,h): consecutive lanes write consecutive 16B -> fully coalesced.
        float4* d4 = reinterpret_cast<float4*>(out + (size_t)m2 * 1024 +
                                               (size_t)r * 32 + h * 16);
        #pragma unroll
        for (int j4 = 0; j4 < 4; ++j4)
            d4[j4] = make_float4(acc[2*j4][0], acc[2*j4][1],
                                 acc[2*j4+1][0], acc[2*j4+1][1]);
    }
}

extern "C" void kernel_launch(void* const* d_in, const int* in_sizes, int n_in,
                              void* d_out, int out_size, void* d_ws, size_t ws_size,
                              hipStream_t stream) {
    const float* P = (const float*)d_in[0];
    float* out = (float*)d_out;
    const int nmat = in_sizes[0] / 1024;     // 32768
    const int nblocks = (nmat + 15) / 16;    // 16 matrices per 256-thread block
    logeig_kernel<<<nblocks, 256, 0, stream>>>(P, out, nmat);
}

// Round 5
// 4417.523 us; speedup vs baseline: 2.3058x; 2.3058x over previous
//
#include <hip/hip_runtime.h>

// LogEig of 32768 SPD 32x32 fp32 matrices via one-sided Jacobi.
//
// v6 = v5 with the register budget fixed. v5's __launch_bounds__(256,8)
// imposed a 64-VGPR cap (512/8); the kernel needs ~56-80, so the compiler
// spilled X[16]/Y[16] to scratch: VGPR_Count 32, FETCH 16.6 GB (was 65 MB),
// 51 GB of HBM traffic, 10186 us. __launch_bounds__(256,6) gives an ~84-VGPR
// budget -> zero spill, occupancy still 24-32 waves/CU (75-100%) vs v3b's 12
// (1-wave workgroups were workgroup-slot capped, proven by v5's 70% occ).
// v5 also proved the 256-thread/pkfma restructure bit-correct (absmax
// identical to v3b).
//
// Structure recap: per wave: 4 matrices; 16 lanes/matrix; lane `sub` owns
// columns at positions (2*sub, 2*sub+1). Even rounds rotate the lane-local
// pair (zero communication). Odd rounds pair (pos 2s+1, 2s+2): fetch
// partner with DPP row_shl:1 (lane i <- i+1), ship the updated column back
// with row_shr:1 (lane i <- i-1). Always-swap => odd-even transposition
// covers all 496 pairs exactly once per 32-round sweep. DPP rows (16 lanes)
// never cross matrix/wave boundaries. Main loop issues ZERO DS instructions.
// All v2f math is __builtin_elementwise_fma on pre-broadcast {cr,cr}/{sr,sr}
// vectors to maximize v_pk_fma_f32/v_pk_mul_f32 selection.

typedef float v2f __attribute__((ext_vector_type(2)));

#define SWEEPS 10

static __device__ __forceinline__ v2f pkfma(v2f a, v2f b, v2f c) {
    return __builtin_elementwise_fma(a, b, c);
}

static __device__ __forceinline__ float dpp_next(float v) {
    // lane i <- lane i+1 within its 16-lane row (row_shl:1).
    // Row tail (lane 15) has no source -> bound_ctrl=false keeps own value.
    return __builtin_bit_cast(float, __builtin_amdgcn_update_dpp(
        __builtin_bit_cast(int, v), __builtin_bit_cast(int, v),
        0x101 /*row_shl:1*/, 0xF, 0xF, false));
}
static __device__ __forceinline__ float dpp_ship(float oldv, float srcv) {
    // lane i <- srcv from lane i-1 within its row (row_shr:1).
    // Row head (lane 0) has no source -> keeps oldv (position 0 idle).
    return __builtin_bit_cast(float, __builtin_amdgcn_update_dpp(
        __builtin_bit_cast(int, oldv), __builtin_bit_cast(int, srcv),
        0x111 /*row_shr:1*/, 0xF, 0xF, false));
}

static __device__ __forceinline__ void make_rot(float dot, float gpp, float gqq,
                                                float& cr, float& sr) {
    // Jacobi rotation zeroing Gram(p,q); small root t of t^2 + 2*tau*t - 1 = 0.
    const float tau = (gqq - gpp) * 0.5f * __builtin_amdgcn_rcpf(dot);
    const float at  = fabsf(tau);
    float t = __builtin_amdgcn_rcpf(at + __builtin_amdgcn_sqrtf(fmaf(at, at, 1.f)));
    t = copysignf(t, tau);
    if (fabsf(dot) < 1e-37f) t = 0.f;   // skip / kill 0/0 NaN
    cr = __builtin_amdgcn_rsqf(fmaf(t, t, 1.f));
    sr = t * cr;
}

__global__ __launch_bounds__(256, 6) void logeig_kernel(const float* __restrict__ P,
                                                        float* __restrict__ out,
                                                        int nmat) {
    const int tid  = threadIdx.x;     // 0..255
    const int lane = tid & 63;        // lane within wave
    const int wv   = tid >> 6;        // wave within block (0..3)
    const int sub  = lane & 15;       // lane within matrix
    const int mg   = lane >> 4;       // matrix slot within wave (0..3)
    int mat = blockIdx.x * 16 + wv * 4 + mg;
    if (mat >= nmat) mat = nmat - 1;

    // Load columns 2*sub and 2*sub+1 (P symmetric -> column == row, contiguous).
    v2f X[16], Y[16];
    {
        const float4* s4 =
            reinterpret_cast<const float4*>(P + (size_t)mat * 1024 + (size_t)sub * 64);
        #pragma unroll
        for (int k = 0; k < 8; ++k) {
            float4 v = s4[k];
            X[2*k]   = (v2f){v.x, v.y};
            X[2*k+1] = (v2f){v.z, v.w};
        }
        #pragma unroll
        for (int k = 0; k < 8; ++k) {
            float4 v = s4[8 + k];
            Y[2*k]   = (v2f){v.x, v.y};
            Y[2*k+1] = (v2f){v.z, v.w};
        }
    }

    const bool tail = (sub == 15);    // its Y = position 31: idle in odd rounds

    #pragma unroll 1
    for (int sweep = 0; sweep < SWEEPS; ++sweep) {
        #pragma unroll 1
        for (int rr = 0; rr < 16; ++rr) {
            // ---------- even round: local pair (u = X @ pos 2s, v = Y @ pos 2s+1)
            {
                v2f dA={0,0}, dB={0,0}, pA={0,0}, pB={0,0}, qA={0,0}, qB={0,0};
                #pragma unroll
                for (int k = 0; k < 16; k += 2) {
                    dA = pkfma(X[k],   Y[k],   dA);
                    pA = pkfma(X[k],   X[k],   pA);
                    qA = pkfma(Y[k],   Y[k],   qA);
                    dB = pkfma(X[k+1], Y[k+1], dB);
                    pB = pkfma(X[k+1], X[k+1], pB);
                    qB = pkfma(Y[k+1], Y[k+1], qB);
                }
                v2f dT = dA + dB, pT = pA + pB, qT = qA + qB;
                float cr, sr;
                make_rot(dT[0] + dT[1], pT[0] + pT[1], qT[0] + qT[1], cr, sr);
                const v2f crv = {cr, cr}, srv = {sr, sr}, nsv = {-sr, -sr};
                // always-swap: pos 2s <- v' = cr*Y + sr*X ; pos 2s+1 <- u' = cr*X - sr*Y
                #pragma unroll
                for (int k = 0; k < 16; ++k) {
                    const v2f xo = X[k];
                    X[k] = pkfma(crv, Y[k], srv * xo);   // cr*Y + sr*xo
                    Y[k] = pkfma(nsv, Y[k], crv * xo);   // cr*xo - sr*Y
                }
            }
            // ---------- odd round: pair (u = Y_s @ pos 2s+1, v = X_{s+1} @ pos 2s+2)
            {
                v2f dA={0,0}, dB={0,0}, pA={0,0}, pB={0,0}, qA={0,0}, qB={0,0};
                #pragma unroll
                for (int k = 0; k < 16; ++k) {
                    v2f o;
                    o[0] = dpp_next(X[k][0]);
                    o[1] = dpp_next(X[k][1]);
                    if (k & 1) { dB = pkfma(Y[k], o, dB); qB = pkfma(o, o, qB);
                                 pB = pkfma(Y[k], Y[k], pB); }
                    else       { dA = pkfma(Y[k], o, dA); qA = pkfma(o, o, qA);
                                 pA = pkfma(Y[k], Y[k], pA); }
                }
                v2f dT = dA + dB, pT = pA + pB, qT = qA + qB;
                float cr, sr;
                make_rot(dT[0] + dT[1], pT[0] + pT[1], qT[0] + qT[1], cr, sr);
                // boundary: position 31 (tail lane's Y) is unpaired -> (cr,sr)=(0,1)
                // makes Y' = Y exactly; its shipped u' dies at the row boundary.
                cr = tail ? 0.f : cr;
                sr = tail ? 1.f : sr;
                const v2f crv = {cr, cr}, srv = {sr, sr}, nsv = {-sr, -sr};
                #pragma unroll
                for (int k = 0; k < 16; ++k) {
                    v2f o;                      // refetch: X untouched until recv below
                    o[0] = dpp_next(X[k][0]);
                    o[1] = dpp_next(X[k][1]);
                    const v2f yo = Y[k];
                    Y[k] = pkfma(crv, o, srv * yo);      // v' = cr*o + sr*yo stays here
                    v2f u = pkfma(crv, yo, nsv * o);     // u' = cr*yo - sr*o ships right
                    X[k][0] = dpp_ship(X[k][0], u[0]);   // lane 0 keeps X (pos 0 idle)
                    X[k][1] = dpp_ship(X[k][1], u[1]);
                }
            }
        }
    }

    // ---------- epilogue: sigma, log, normalize; X = sum_c l_c u_c u_c^T ----------
    float nx2, ny2;
    {
        v2f a={0,0}, b={0,0};
        #pragma unroll
        for (int k = 0; k < 16; k += 2) { a = pkfma(X[k], X[k], a); b = pkfma(X[k+1], X[k+1], b); }
        v2f t = a + b; nx2 = t[0] + t[1];
    }
    {
        v2f a={0,0}, b={0,0};
        #pragma unroll
        for (int k = 0; k < 16; k += 2) { a = pkfma(Y[k], Y[k], a); b = pkfma(Y[k+1], Y[k+1], b); }
        v2f t = a + b; ny2 = t[0] + t[1];
    }
    const float invx = __builtin_amdgcn_rsqf(nx2);               // 1/sigma
    const float invy = __builtin_amdgcn_rsqf(ny2);
    const float lgx  = 0.34657359f * __builtin_amdgcn_logf(nx2); // ln(sigma)
    const float lgy  = 0.34657359f * __builtin_amdgcn_logf(ny2);

    // Per-wave LDS slice; one matrix per phase. 4 x 32 x 36 x 4B = 18432 B;
    // at 6-8 blocks/CU this is 110-147 KB <= 160 KB -> LDS never binds.
    // Row stride 36 keeps 16-float halves 16B-aligned; log(eig) in pad [c][33].
    __shared__ __align__(16) float S[4][32][36];

    const int r = lane >> 1;       // output row this lane accumulates
    const int h = lane & 1;        // which 16-float half of that row

    #pragma unroll 1
    for (int ph = 0; ph < 4; ++ph) {
        __syncthreads();           // protect S reuse across phases (uniform count)
        if (mg == ph) {
            #pragma unroll
            for (int k = 0; k < 16; ++k) {
                *reinterpret_cast<v2f*>(&S[wv][2*sub][2*k])   = X[k] * invx;
                *reinterpret_cast<v2f*>(&S[wv][2*sub+1][2*k]) = Y[k] * invy;
            }
            S[wv][2*sub][33]   = lgx;
            S[wv][2*sub+1][33] = lgy;
        }
        __syncthreads();

        // All 64 lanes of the wave cooperate on its matrix `ph`.
        v2f acc[8];
        #pragma unroll
        for (int j = 0; j < 8; ++j) acc[j] = (v2f){0.f, 0.f};
        #pragma unroll 4
        for (int c = 0; c < 32; ++c) {
            const float m = S[wv][c][r] * S[wv][c][33];   // u_c[r] * log(lambda_c)
            const v2f mv = {m, m};
            const float4* row4 = reinterpret_cast<const float4*>(&S[wv][c][h * 16]);
            #pragma unroll
            for (int j4 = 0; j4 < 4; ++j4) {
                float4 v = row4[j4];
                acc[2*j4]   = pkfma(mv, (v2f){v.x, v.y}, acc[2*j4]);
                acc[2*j4+1] = pkfma(mv, (v2f){v.z, v.w}, acc[2*j4+1]);
            }
        }
        int m2 = blockIdx.x * 16 + wv * 4 + ph;
        if (m2 >= nmat) m2 = nmat - 1;
        // lane -> (r,h): consecutive lanes write consecutive 16B -> fully coalesced.
        float4* d4 = reinterpret_cast<float4*>(out + (size_t)m2 * 1024 +
                                               (size_t)r * 32 + h * 16);
        #pragma unroll
        for (int j4 = 0; j4 < 4; ++j4)
            d4[j4] = make_float4(acc[2*j4][0], acc[2*j4][1],
                                 acc[2*j4+1][0], acc[2*j4+1][1]);
    }
}

extern "C" void kernel_launch(void* const* d_in, const int* in_sizes, int n_in,
                              void* d_out, int out_size, void* d_ws, size_t ws_size,
                              hipStream_t stream) {
    const float* P = (const float*)d_in[0];
    float* out = (float*)d_out;
    const int nmat = in_sizes[0] / 1024;     // 32768
    const int nblocks = (nmat + 15) / 16;    // 16 matrices per 256-thread block
    logeig_kernel<<<nblocks, 256, 0, stream>>>(P, out, nmat);
}

// Round 6
// 1190.442 us; speedup vs baseline: 8.5564x; 3.7108x over previous
//
#include <hip/hip_runtime.h>

// LogEig of 32768 SPD 32x32 fp32 matrices via one-sided Jacobi.
//
// v7 = v6 with the register budget actually sized to the kernel.
// History of the occupancy/spill ledger (unified VGPR+AGPR file, budget =
// 512 / waves_per_eu_min; rocprof's VGPR_Count shows only the arch half):
//   v3b (64,4):  budget 128 -> fit (56 arch + AGPRs), no spill, 1120 us,
//                but 1-wave workgroups slot-capped at ~12 waves/CU (38%).
//   v5 (256,8):  budget  64 -> X/Y spilled to scratch, 51 GB HBM, 10186 us.
//   v6 (256,6):  budget ~80 -> still short of the ~112-reg footprint,
//                21.5 GB HBM, 4417 us. Monotone recovery 64->80 budget
//                confirms the true footprint is ~96-112 regs.
//   v7 (256,4):  budget 128 >= footprint -> spill-free AND 4-wave
//                workgroups -> 16 waves/CU (50%), beating v3b's 12.
//                Also frees the allocator from AGPR shuttling
//                (v_accvgpr_read/write round-trips), the best explanation
//                for v3b's ~960 measured instr/round-pair vs ~660 counted.
//
// Structure recap: per wave: 4 matrices; 16 lanes/matrix; lane `sub` owns
// columns at positions (2*sub, 2*sub+1). Even rounds rotate the lane-local
// pair (zero communication). Odd rounds pair (pos 2s+1, 2s+2): fetch
// partner with DPP row_shl:1 (lane i <- i+1), ship the updated column back
// with row_shr:1 (lane i <- i-1). Always-swap => odd-even transposition
// covers all 496 pairs exactly once per 32-round sweep. DPP rows (16 lanes)
// never cross matrix/wave boundaries. Main loop issues ZERO DS instructions.
// All v2f math is __builtin_elementwise_fma on pre-broadcast {cr,cr}/{sr,sr}
// vectors to maximize v_pk_fma_f32/v_pk_mul_f32 selection. Bit-correctness
// of this exact structure proven in v5/v6 (absmax identical to v3b).

typedef float v2f __attribute__((ext_vector_type(2)));

#define SWEEPS 10

static __device__ __forceinline__ v2f pkfma(v2f a, v2f b, v2f c) {
    return __builtin_elementwise_fma(a, b, c);
}

static __device__ __forceinline__ float dpp_next(float v) {
    // lane i <- lane i+1 within its 16-lane row (row_shl:1).
    // Row tail (lane 15) has no source -> bound_ctrl=false keeps own value.
    return __builtin_bit_cast(float, __builtin_amdgcn_update_dpp(
        __builtin_bit_cast(int, v), __builtin_bit_cast(int, v),
        0x101 /*row_shl:1*/, 0xF, 0xF, false));
}
static __device__ __forceinline__ float dpp_ship(float oldv, float srcv) {
    // lane i <- srcv from lane i-1 within its row (row_shr:1).
    // Row head (lane 0) has no source -> keeps oldv (position 0 idle).
    return __builtin_bit_cast(float, __builtin_amdgcn_update_dpp(
        __builtin_bit_cast(int, oldv), __builtin_bit_cast(int, srcv),
        0x111 /*row_shr:1*/, 0xF, 0xF, false));
}

static __device__ __forceinline__ void make_rot(float dot, float gpp, float gqq,
                                                float& cr, float& sr) {
    // Jacobi rotation zeroing Gram(p,q); small root t of t^2 + 2*tau*t - 1 = 0.
    const float tau = (gqq - gpp) * 0.5f * __builtin_amdgcn_rcpf(dot);
    const float at  = fabsf(tau);
    float t = __builtin_amdgcn_rcpf(at + __builtin_amdgcn_sqrtf(fmaf(at, at, 1.f)));
    t = copysignf(t, tau);
    if (fabsf(dot) < 1e-37f) t = 0.f;   // skip / kill 0/0 NaN
    cr = __builtin_amdgcn_rsqf(fmaf(t, t, 1.f));
    sr = t * cr;
}

__global__ __launch_bounds__(256, 4) void logeig_kernel(const float* __restrict__ P,
                                                        float* __restrict__ out,
                                                        int nmat) {
    const int tid  = threadIdx.x;     // 0..255
    const int lane = tid & 63;        // lane within wave
    const int wv   = tid >> 6;        // wave within block (0..3)
    const int sub  = lane & 15;       // lane within matrix
    const int mg   = lane >> 4;       // matrix slot within wave (0..3)
    int mat = blockIdx.x * 16 + wv * 4 + mg;
    if (mat >= nmat) mat = nmat - 1;

    // Load columns 2*sub and 2*sub+1 (P symmetric -> column == row, contiguous).
    v2f X[16], Y[16];
    {
        const float4* s4 =
            reinterpret_cast<const float4*>(P + (size_t)mat * 1024 + (size_t)sub * 64);
        #pragma unroll
        for (int k = 0; k < 8; ++k) {
            float4 v = s4[k];
            X[2*k]   = (v2f){v.x, v.y};
            X[2*k+1] = (v2f){v.z, v.w};
        }
        #pragma unroll
        for (int k = 0; k < 8; ++k) {
            float4 v = s4[8 + k];
            Y[2*k]   = (v2f){v.x, v.y};
            Y[2*k+1] = (v2f){v.z, v.w};
        }
    }

    const bool tail = (sub == 15);    // its Y = position 31: idle in odd rounds

    #pragma unroll 1
    for (int sweep = 0; sweep < SWEEPS; ++sweep) {
        #pragma unroll 1
        for (int rr = 0; rr < 16; ++rr) {
            // ---------- even round: local pair (u = X @ pos 2s, v = Y @ pos 2s+1)
            {
                v2f dA={0,0}, dB={0,0}, pA={0,0}, pB={0,0}, qA={0,0}, qB={0,0};
                #pragma unroll
                for (int k = 0; k < 16; k += 2) {
                    dA = pkfma(X[k],   Y[k],   dA);
                    pA = pkfma(X[k],   X[k],   pA);
                    qA = pkfma(Y[k],   Y[k],   qA);
                    dB = pkfma(X[k+1], Y[k+1], dB);
                    pB = pkfma(X[k+1], X[k+1], pB);
                    qB = pkfma(Y[k+1], Y[k+1], qB);
                }
                v2f dT = dA + dB, pT = pA + pB, qT = qA + qB;
                float cr, sr;
                make_rot(dT[0] + dT[1], pT[0] + pT[1], qT[0] + qT[1], cr, sr);
                const v2f crv = {cr, cr}, srv = {sr, sr}, nsv = {-sr, -sr};
                // always-swap: pos 2s <- v' = cr*Y + sr*X ; pos 2s+1 <- u' = cr*X - sr*Y
                #pragma unroll
                for (int k = 0; k < 16; ++k) {
                    const v2f xo = X[k];
                    X[k] = pkfma(crv, Y[k], srv * xo);   // cr*Y + sr*xo
                    Y[k] = pkfma(nsv, Y[k], crv * xo);   // cr*xo - sr*Y
                }
            }
            // ---------- odd round: pair (u = Y_s @ pos 2s+1, v = X_{s+1} @ pos 2s+2)
            {
                v2f dA={0,0}, dB={0,0}, pA={0,0}, pB={0,0}, qA={0,0}, qB={0,0};
                #pragma unroll
                for (int k = 0; k < 16; ++k) {
                    v2f o;
                    o[0] = dpp_next(X[k][0]);
                    o[1] = dpp_next(X[k][1]);
                    if (k & 1) { dB = pkfma(Y[k], o, dB); qB = pkfma(o, o, qB);
                                 pB = pkfma(Y[k], Y[k], pB); }
                    else       { dA = pkfma(Y[k], o, dA); qA = pkfma(o, o, qA);
                                 pA = pkfma(Y[k], Y[k], pA); }
                }
                v2f dT = dA + dB, pT = pA + pB, qT = qA + qB;
                float cr, sr;
                make_rot(dT[0] + dT[1], pT[0] + pT[1], qT[0] + qT[1], cr, sr);
                // boundary: position 31 (tail lane's Y) is unpaired -> (cr,sr)=(0,1)
                // makes Y' = Y exactly; its shipped u' dies at the row boundary.
                cr = tail ? 0.f : cr;
                sr = tail ? 1.f : sr;
                const v2f crv = {cr, cr}, srv = {sr, sr}, nsv = {-sr, -sr};
                #pragma unroll
                for (int k = 0; k < 16; ++k) {
                    v2f o;                      // refetch: X untouched until recv below
                    o[0] = dpp_next(X[k][0]);
                    o[1] = dpp_next(X[k][1]);
                    const v2f yo = Y[k];
                    Y[k] = pkfma(crv, o, srv * yo);      // v' = cr*o + sr*yo stays here
                    v2f u = pkfma(crv, yo, nsv * o);     // u' = cr*yo - sr*o ships right
                    X[k][0] = dpp_ship(X[k][0], u[0]);   // lane 0 keeps X (pos 0 idle)
                    X[k][1] = dpp_ship(X[k][1], u[1]);
                }
            }
        }
    }

    // ---------- epilogue: sigma, log, normalize; X = sum_c l_c u_c u_c^T ----------
    float nx2, ny2;
    {
        v2f a={0,0}, b={0,0};
        #pragma unroll
        for (int k = 0; k < 16; k += 2) { a = pkfma(X[k], X[k], a); b = pkfma(X[k+1], X[k+1], b); }
        v2f t = a + b; nx2 = t[0] + t[1];
    }
    {
        v2f a={0,0}, b={0,0};
        #pragma unroll
        for (int k = 0; k < 16; k += 2) { a = pkfma(Y[k], Y[k], a); b = pkfma(Y[k+1], Y[k+1], b); }
        v2f t = a + b; ny2 = t[0] + t[1];
    }
    const float invx = __builtin_amdgcn_rsqf(nx2);               // 1/sigma
    const float invy = __builtin_amdgcn_rsqf(ny2);
    const float lgx  = 0.34657359f * __builtin_amdgcn_logf(nx2); // ln(sigma)
    const float lgy  = 0.34657359f * __builtin_amdgcn_logf(ny2);

    // Per-wave LDS slice; one matrix per phase. 4 x 32 x 36 x 4B = 18432 B;
    // at 4 blocks/CU = 73.7 KB <= 160 KB -> LDS never binds.
    // Row stride 36 keeps 16-float halves 16B-aligned; log(eig) in pad [c][33].
    __shared__ __align__(16) float S[4][32][36];

    const int r = lane >> 1;       // output row this lane accumulates
    const int h = lane & 1;        // which 16-float half of that row

    #pragma unroll 1
    for (int ph = 0; ph < 4; ++ph) {
        __syncthreads();           // protect S reuse across phases (uniform count)
        if (mg == ph) {
            #pragma unroll
            for (int k = 0; k < 16; ++k) {
                *reinterpret_cast<v2f*>(&S[wv][2*sub][2*k])   = X[k] * invx;
                *reinterpret_cast<v2f*>(&S[wv][2*sub+1][2*k]) = Y[k] * invy;
            }
            S[wv][2*sub][33]   = lgx;
            S[wv][2*sub+1][33] = lgy;
        }
        __syncthreads();

        // All 64 lanes of the wave cooperate on its matrix `ph`.
        v2f acc[8];
        #pragma unroll
        for (int j = 0; j < 8; ++j) acc[j] = (v2f){0.f, 0.f};
        #pragma unroll 4
        for (int c = 0; c < 32; ++c) {
            const float m = S[wv][c][r] * S[wv][c][33];   // u_c[r] * log(lambda_c)
            const v2f mv = {m, m};
            const float4* row4 = reinterpret_cast<const float4*>(&S[wv][c][h * 16]);
            #pragma unroll
            for (int j4 = 0; j4 < 4; ++j4) {
                float4 v = row4[j4];
                acc[2*j4]   = pkfma(mv, (v2f){v.x, v.y}, acc[2*j4]);
                acc[2*j4+1] = pkfma(mv, (v2f){v.z, v.w}, acc[2*j4+1]);
            }
        }
        int m2 = blockIdx.x * 16 + wv * 4 + ph;
        if (m2 >= nmat) m2 = nmat - 1;
        // lane -> (r,h): consecutive lanes write consecutive 16B -> fully coalesced.
        float4* d4 = reinterpret_cast<float4*>(out + (size_t)m2 * 1024 +
                                               (size_t)r * 32 + h * 16);
        #pragma unroll
        for (int j4 = 0; j4 < 4; ++j4)
            d4[j4] = make_float4(acc[2*j4][0], acc[2*j4][1],
                                 acc[2*j4+1][0], acc[2*j4+1][1]);
    }
}

extern "C" void kernel_launch(void* const* d_in, const int* in_sizes, int n_in,
                              void* d_out, int out_size, void* d_ws, size_t ws_size,
                              hipStream_t stream) {
    const float* P = (const float*)d_in[0];
    float* out = (float*)d_out;
    const int nmat = in_sizes[0] / 1024;     // 32768
    const int nblocks = (nmat + 15) / 16;    // 16 matrices per 256-thread block
    logeig_kernel<<<nblocks, 256, 0, stream>>>(P, out, nmat);
}

// Round 7
// 1133.253 us; speedup vs baseline: 8.9882x; 1.0505x over previous
//
#include <hip/hip_runtime.h>

// LogEig of 32768 SPD 32x32 fp32 matrices via one-sided Jacobi.
//
// v8 = v7 with the packed math FORCED. v7's counters implied ~1000 VALU
// instrs/round-pair vs a ~356 packed-form hand count: the v2f
// __builtin_elementwise_fma was scalarizing to 2x v_fma_f32, and each
// bound_ctrl=0 self-sourced DPP fetch cost 2 instrs (mov + mov_dpp).
// Changes (nothing else touched; SWEEPS=10, layout, budget identical):
//  (a) inline-asm v_pk_fma_f32 / v_pk_mul_f32 for all main-loop v2f math
//      (VOP3P guaranteed; halves the FMA stream).
//  (b) partner fetch DPP uses bound_ctrl:1 (invalid lane -> 0.0) -> single
//      v_mov_b32_dpp. Only the tail lane (sub=15) is invalid; its rotation
//      is forced to (cr,sr)=(0,1) so o=0.0 is algebraically identical to
//      the old kept-value path (and cannot inject NaN via 0*garbage).
//      The ship keeps bound_ctrl:0 (dest already holds old -> 1 instr).
//
// Ledger: v3b 1120us (1-wave wg, 38% occ, VALU 91%); v5 (256,8) 64-reg cap
// -> spill, 10186us; v6 (256,6) ~80-reg cap -> spill, 4417us; v7 (256,4)
// 128-reg budget -> no spill, 1190us, but occupancy STILL 38% and VALU 90%
// -> occupancy lever dead, instruction count is the only lever left.
//
// Structure recap: per wave: 4 matrices; 16 lanes/matrix; lane `sub` owns
// columns at positions (2*sub, 2*sub+1). Even rounds rotate the lane-local
// pair (zero communication). Odd rounds pair (pos 2s+1, 2s+2): fetch
// partner with DPP row_shl:1 (lane i <- i+1), ship the updated column back
// with row_shr:1 (lane i <- i-1). Always-swap => odd-even transposition
// covers all 496 pairs exactly once per 32-round sweep. DPP rows (16 lanes)
// never cross matrix/wave boundaries. Main loop issues ZERO DS instructions.

typedef float v2f __attribute__((ext_vector_type(2)));

#define SWEEPS 10

// ---- forced-packed VOP3P helpers (defaults: op_sel 000, op_sel_hi 111) ----
static __device__ __forceinline__ void pk_acc(v2f& acc, v2f a, v2f b) {
    asm("v_pk_fma_f32 %0, %1, %2, %0" : "+v"(acc) : "v"(a), "v"(b));
}
static __device__ __forceinline__ v2f pk_mul(v2f a, v2f b) {
    v2f d; asm("v_pk_mul_f32 %0, %1, %2" : "=v"(d) : "v"(a), "v"(b)); return d;
}
static __device__ __forceinline__ v2f pk_fma(v2f a, v2f b, v2f c) {
    v2f d; asm("v_pk_fma_f32 %0, %1, %2, %3" : "=v"(d) : "v"(a), "v"(b), "v"(c)); return d;
}

static __device__ __forceinline__ float dpp_next0(float v) {
    // lane i <- lane i+1 within its 16-lane row (row_shl:1), bound_ctrl:1:
    // invalid lane (row tail, sub=15) reads 0.0. Single v_mov_b32_dpp.
    return __builtin_bit_cast(float, __builtin_amdgcn_update_dpp(
        0, __builtin_bit_cast(int, v), 0x101 /*row_shl:1*/, 0xF, 0xF, true));
}
static __device__ __forceinline__ float dpp_ship(float oldv, float srcv) {
    // lane i <- srcv from lane i-1 (row_shr:1); row head keeps oldv.
    // Dest register already holds oldv -> single v_mov_b32_dpp.
    return __builtin_bit_cast(float, __builtin_amdgcn_update_dpp(
        __builtin_bit_cast(int, oldv), __builtin_bit_cast(int, srcv),
        0x111 /*row_shr:1*/, 0xF, 0xF, false));
}

static __device__ __forceinline__ void make_rot(float dot, float gpp, float gqq,
                                                float& cr, float& sr) {
    // Jacobi rotation zeroing Gram(p,q); small root t of t^2 + 2*tau*t - 1 = 0.
    const float tau = (gqq - gpp) * 0.5f * __builtin_amdgcn_rcpf(dot);
    const float at  = fabsf(tau);
    float t = __builtin_amdgcn_rcpf(at + __builtin_amdgcn_sqrtf(fmaf(at, at, 1.f)));
    t = copysignf(t, tau);
    if (fabsf(dot) < 1e-37f) t = 0.f;   // skip / kill 0/0 NaN
    cr = __builtin_amdgcn_rsqf(fmaf(t, t, 1.f));
    sr = t * cr;
}

__global__ __launch_bounds__(256, 4) void logeig_kernel(const float* __restrict__ P,
                                                        float* __restrict__ out,
                                                        int nmat) {
    const int tid  = threadIdx.x;     // 0..255
    const int lane = tid & 63;        // lane within wave
    const int wv   = tid >> 6;        // wave within block (0..3)
    const int sub  = lane & 15;       // lane within matrix
    const int mg   = lane >> 4;       // matrix slot within wave (0..3)
    int mat = blockIdx.x * 16 + wv * 4 + mg;
    if (mat >= nmat) mat = nmat - 1;

    // Load columns 2*sub and 2*sub+1 (P symmetric -> column == row, contiguous).
    v2f X[16], Y[16];
    {
        const float4* s4 =
            reinterpret_cast<const float4*>(P + (size_t)mat * 1024 + (size_t)sub * 64);
        #pragma unroll
        for (int k = 0; k < 8; ++k) {
            float4 v = s4[k];
            X[2*k]   = (v2f){v.x, v.y};
            X[2*k+1] = (v2f){v.z, v.w};
        }
        #pragma unroll
        for (int k = 0; k < 8; ++k) {
            float4 v = s4[8 + k];
            Y[2*k]   = (v2f){v.x, v.y};
            Y[2*k+1] = (v2f){v.z, v.w};
        }
    }

    const bool tail = (sub == 15);    // its Y = position 31: idle in odd rounds

    #pragma unroll 1
    for (int sweep = 0; sweep < SWEEPS; ++sweep) {
        #pragma unroll 1
        for (int rr = 0; rr < 16; ++rr) {
            // ---------- even round: local pair (u = X @ pos 2s, v = Y @ pos 2s+1)
            {
                v2f dA={0,0}, dB={0,0}, pA={0,0}, pB={0,0}, qA={0,0}, qB={0,0};
                #pragma unroll
                for (int k = 0; k < 16; k += 2) {
                    pk_acc(dA, X[k],   Y[k]);
                    pk_acc(pA, X[k],   X[k]);
                    pk_acc(qA, Y[k],   Y[k]);
                    pk_acc(dB, X[k+1], Y[k+1]);
                    pk_acc(pB, X[k+1], X[k+1]);
                    pk_acc(qB, Y[k+1], Y[k+1]);
                }
                v2f dT = dA + dB, pT = pA + pB, qT = qA + qB;
                float cr, sr;
                make_rot(dT[0] + dT[1], pT[0] + pT[1], qT[0] + qT[1], cr, sr);
                const v2f crv = {cr, cr}, srv = {sr, sr}, nsv = {-sr, -sr};
                // always-swap: pos 2s <- v' = cr*Y + sr*X ; pos 2s+1 <- u' = cr*X - sr*Y
                #pragma unroll
                for (int k = 0; k < 16; ++k) {
                    const v2f xo = X[k];
                    X[k] = pk_fma(crv, Y[k], pk_mul(srv, xo));   // cr*Y + sr*xo
                    Y[k] = pk_fma(nsv, Y[k], pk_mul(crv, xo));   // cr*xo - sr*Y
                }
            }
            // ---------- odd round: pair (u = Y_s @ pos 2s+1, v = X_{s+1} @ pos 2s+2)
            {
                v2f dA={0,0}, dB={0,0}, pA={0,0}, pB={0,0}, qA={0,0}, qB={0,0};
                #pragma unroll
                for (int k = 0; k < 16; ++k) {
                    v2f o;
                    o[0] = dpp_next0(X[k][0]);
                    o[1] = dpp_next0(X[k][1]);
                    if (k & 1) { pk_acc(dB, Y[k], o); pk_acc(qB, o, o);
                                 pk_acc(pB, Y[k], Y[k]); }
                    else       { pk_acc(dA, Y[k], o); pk_acc(qA, o, o);
                                 pk_acc(pA, Y[k], Y[k]); }
                }
                v2f dT = dA + dB, pT = pA + pB, qT = qA + qB;
                float cr, sr;
                make_rot(dT[0] + dT[1], pT[0] + pT[1], qT[0] + qT[1], cr, sr);
                // boundary: position 31 (tail lane's Y) is unpaired -> (cr,sr)=(0,1)
                // makes Y' = Y exactly; its shipped u' dies at the row boundary.
                cr = tail ? 0.f : cr;
                sr = tail ? 1.f : sr;
                const v2f crv = {cr, cr}, srv = {sr, sr}, nsv = {-sr, -sr};
                #pragma unroll
                for (int k = 0; k < 16; ++k) {
                    v2f o;                      // refetch: X untouched until recv below
                    o[0] = dpp_next0(X[k][0]);
                    o[1] = dpp_next0(X[k][1]);
                    const v2f yo = Y[k];
                    Y[k]  = pk_fma(crv, o,  pk_mul(srv, yo));  // v' = cr*o + sr*yo
                    v2f u = pk_fma(crv, yo, pk_mul(nsv, o));   // u' = cr*yo - sr*o
                    X[k][0] = dpp_ship(X[k][0], u[0]);   // lane 0 keeps X (pos 0 idle)
                    X[k][1] = dpp_ship(X[k][1], u[1]);
                }
            }
        }
    }

    // ---------- epilogue: sigma, log, normalize; X = sum_c l_c u_c u_c^T ----------
    float nx2, ny2;
    {
        v2f a={0,0}, b={0,0};
        #pragma unroll
        for (int k = 0; k < 16; k += 2) { pk_acc(a, X[k], X[k]); pk_acc(b, X[k+1], X[k+1]); }
        v2f t = a + b; nx2 = t[0] + t[1];
    }
    {
        v2f a={0,0}, b={0,0};
        #pragma unroll
        for (int k = 0; k < 16; k += 2) { pk_acc(a, Y[k], Y[k]); pk_acc(b, Y[k+1], Y[k+1]); }
        v2f t = a + b; ny2 = t[0] + t[1];
    }
    const float invx = __builtin_amdgcn_rsqf(nx2);               // 1/sigma
    const float invy = __builtin_amdgcn_rsqf(ny2);
    const float lgx  = 0.34657359f * __builtin_amdgcn_logf(nx2); // ln(sigma)
    const float lgy  = 0.34657359f * __builtin_amdgcn_logf(ny2);

    // Per-wave LDS slice; one matrix per phase. 4 x 32 x 36 x 4B = 18432 B;
    // at 4 blocks/CU = 73.7 KB <= 160 KB -> LDS never binds.
    // Row stride 36 keeps 16-float halves 16B-aligned; log(eig) in pad [c][33].
    __shared__ __align__(16) float S[4][32][36];

    const int r = lane >> 1;       // output row this lane accumulates
    const int h = lane & 1;        // which 16-float half of that row

    #pragma unroll 1
    for (int ph = 0; ph < 4; ++ph) {
        __syncthreads();           // protect S reuse across phases (uniform count)
        if (mg == ph) {
            #pragma unroll
            for (int k = 0; k < 16; ++k) {
                *reinterpret_cast<v2f*>(&S[wv][2*sub][2*k])   = X[k] * invx;
                *reinterpret_cast<v2f*>(&S[wv][2*sub+1][2*k]) = Y[k] * invy;
            }
            S[wv][2*sub][33]   = lgx;
            S[wv][2*sub+1][33] = lgy;
        }
        __syncthreads();

        // All 64 lanes of the wave cooperate on its matrix `ph`.
        v2f acc[8];
        #pragma unroll
        for (int j = 0; j < 8; ++j) acc[j] = (v2f){0.f, 0.f};
        #pragma unroll 4
        for (int c = 0; c < 32; ++c) {
            const float m = S[wv][c][r] * S[wv][c][33];   // u_c[r] * log(lambda_c)
            const v2f mv = {m, m};
            const float4* row4 = reinterpret_cast<const float4*>(&S[wv][c][h * 16]);
            #pragma unroll
            for (int j4 = 0; j4 < 4; ++j4) {
                float4 v = row4[j4];
                pk_acc(acc[2*j4],   mv, (v2f){v.x, v.y});
                pk_acc(acc[2*j4+1], mv, (v2f){v.z, v.w});
            }
        }
        int m2 = blockIdx.x * 16 + wv * 4 + ph;
        if (m2 >= nmat) m2 = nmat - 1;
        // lane -> (r,h): consecutive lanes write consecutive 16B -> fully coalesced.
        float4* d4 = reinterpret_cast<float4*>(out + (size_t)m2 * 1024 +
                                               (size_t)r * 32 + h * 16);
        #pragma unroll
        for (int j4 = 0; j4 < 4; ++j4)
            d4[j4] = make_float4(acc[2*j4][0], acc[2*j4][1],
                                 acc[2*j4+1][0], acc[2*j4+1][1]);
    }
}

extern "C" void kernel_launch(void* const* d_in, const int* in_sizes, int n_in,
                              void* d_out, int out_size, void* d_ws, size_t ws_size,
                              hipStream_t stream) {
    const float* P = (const float*)d_in[0];
    float* out = (float*)d_out;
    const int nmat = in_sizes[0] / 1024;     // 32768
    const int nblocks = (nmat + 15) / 16;    // 16 matrices per 256-thread block
    logeig_kernel<<<nblocks, 256, 0, stream>>>(P, out, nmat);
}

// Round 10
// 1084.614 us; speedup vs baseline: 9.3913x; 1.0448x over previous
//
#include <hip/hip_runtime.h>

// LogEig of 32768 SPD 32x32 fp32 matrices via one-sided Jacobi.
//
// v10 = v8 + o2-carry, SWEEPS=10. (v9's SWEEPS=9 probe FAILED: absmax 1.48
// vs 0.0546875 at 10 sweeps -- accuracy is convergence-limited, the
// quadratic-convergence tail still moves ~10^-1 -> 10^-2 between sweeps 9
// and 10, and the lambda~1e-3 jitter-floor eigenvalues amplify it in log.
// 10 sweeps is the floor; the sweep lever is dead.)
// o2-carry is bit-identical dataflow (partner fetched before any mutation
// in the round; v4 ran the same carry at SWEEPS=10 with identical absmax).
//
// Perf ledger (all VALU-bound, VALUBusy ~91%, occupancy pinned ~38%):
//   v2  tournament+bpermute: 1886us (DS-unit wall: 992 bperm/wave-sweep)
//   v3b odd-even + DPP:      1120us (zero DS in main loop)
//   v7  (256,4) no spill:    1190us (occupancy lever dead)
//   v8  forced v_pk_*:       1133us (pk is half-rate on 32-wide FP32 pipe
//                                    -> packing cycle-neutral; -5% was the
//                                    bound_ctrl:1 single-mov DPP fetch)
//   v10 o2-carry:            expect ~1090-1100us (-32 DPP movs/odd round)
//
// Structure recap: per wave: 4 matrices; 16 lanes/matrix; lane `sub` owns
// columns at positions (2*sub, 2*sub+1). Even rounds rotate the lane-local
// pair (zero communication). Odd rounds pair (pos 2s+1, 2s+2): fetch
// partner with DPP row_shl:1 bound_ctrl:1 (lane i <- i+1, tail reads 0.0 --
// dead: tail rotation forced to (0,1)), ship the updated column back with
// row_shr:1 (lane i <- i-1; head keeps own = position 0 idle). Always-swap
// => odd-even transposition covers all 496 pairs exactly once per 32-round
// sweep. DPP rows never cross matrix/wave boundaries. Main loop: ZERO DS.

typedef float v2f __attribute__((ext_vector_type(2)));

#define SWEEPS 10

// ---- forced-packed VOP3P helpers (defaults: op_sel 000, op_sel_hi 111) ----
static __device__ __forceinline__ void pk_acc(v2f& acc, v2f a, v2f b) {
    asm("v_pk_fma_f32 %0, %1, %2, %0" : "+v"(acc) : "v"(a), "v"(b));
}
static __device__ __forceinline__ v2f pk_mul(v2f a, v2f b) {
    v2f d; asm("v_pk_mul_f32 %0, %1, %2" : "=v"(d) : "v"(a), "v"(b)); return d;
}
static __device__ __forceinline__ v2f pk_fma(v2f a, v2f b, v2f c) {
    v2f d; asm("v_pk_fma_f32 %0, %1, %2, %3" : "=v"(d) : "v"(a), "v"(b), "v"(c)); return d;
}

static __device__ __forceinline__ float dpp_next0(float v) {
    // lane i <- lane i+1 within its 16-lane row (row_shl:1), bound_ctrl:1:
    // invalid lane (row tail, sub=15) reads 0.0. Single v_mov_b32_dpp.
    return __builtin_bit_cast(float, __builtin_amdgcn_update_dpp(
        0, __builtin_bit_cast(int, v), 0x101 /*row_shl:1*/, 0xF, 0xF, true));
}
static __device__ __forceinline__ float dpp_ship(float oldv, float srcv) {
    // lane i <- srcv from lane i-1 (row_shr:1); row head keeps oldv.
    // Dest register already holds oldv -> single v_mov_b32_dpp.
    return __builtin_bit_cast(float, __builtin_amdgcn_update_dpp(
        __builtin_bit_cast(int, oldv), __builtin_bit_cast(int, srcv),
        0x111 /*row_shr:1*/, 0xF, 0xF, false));
}

static __device__ __forceinline__ void make_rot(float dot, float gpp, float gqq,
                                                float& cr, float& sr) {
    // Jacobi rotation zeroing Gram(p,q); small root t of t^2 + 2*tau*t - 1 = 0.
    const float tau = (gqq - gpp) * 0.5f * __builtin_amdgcn_rcpf(dot);
    const float at  = fabsf(tau);
    float t = __builtin_amdgcn_rcpf(at + __builtin_amdgcn_sqrtf(fmaf(at, at, 1.f)));
    t = copysignf(t, tau);
    if (fabsf(dot) < 1e-37f) t = 0.f;   // skip / kill 0/0 NaN
    cr = __builtin_amdgcn_rsqf(fmaf(t, t, 1.f));
    sr = t * cr;
}

__global__ __launch_bounds__(256, 4) void logeig_kernel(const float* __restrict__ P,
                                                        float* __restrict__ out,
                                                        int nmat) {
    const int tid  = threadIdx.x;     // 0..255
    const int lane = tid & 63;        // lane within wave
    const int wv   = tid >> 6;        // wave within block (0..3)
    const int sub  = lane & 15;       // lane within matrix
    const int mg   = lane >> 4;       // matrix slot within wave (0..3)
    int mat = blockIdx.x * 16 + wv * 4 + mg;
    if (mat >= nmat) mat = nmat - 1;

    // Load columns 2*sub and 2*sub+1 (P symmetric -> column == row, contiguous).
    v2f X[16], Y[16];
    {
        const float4* s4 =
            reinterpret_cast<const float4*>(P + (size_t)mat * 1024 + (size_t)sub * 64);
        #pragma unroll
        for (int k = 0; k < 8; ++k) {
            float4 v = s4[k];
            X[2*k]   = (v2f){v.x, v.y};
            X[2*k+1] = (v2f){v.z, v.w};
        }
        #pragma unroll
        for (int k = 0; k < 8; ++k) {
            float4 v = s4[8 + k];
            Y[2*k]   = (v2f){v.x, v.y};
            Y[2*k+1] = (v2f){v.z, v.w};
        }
    }

    const bool tail = (sub == 15);    // its Y = position 31: idle in odd rounds

    #pragma unroll 1
    for (int sweep = 0; sweep < SWEEPS; ++sweep) {
        #pragma unroll 1
        for (int rr = 0; rr < 16; ++rr) {
            // ---------- even round: local pair (u = X @ pos 2s, v = Y @ pos 2s+1)
            {
                v2f dA={0,0}, dB={0,0}, pA={0,0}, pB={0,0}, qA={0,0}, qB={0,0};
                #pragma unroll
                for (int k = 0; k < 16; k += 2) {
                    pk_acc(dA, X[k],   Y[k]);
                    pk_acc(pA, X[k],   X[k]);
                    pk_acc(qA, Y[k],   Y[k]);
                    pk_acc(dB, X[k+1], Y[k+1]);
                    pk_acc(pB, X[k+1], X[k+1]);
                    pk_acc(qB, Y[k+1], Y[k+1]);
                }
                v2f dT = dA + dB, pT = pA + pB, qT = qA + qB;
                float cr, sr;
                make_rot(dT[0] + dT[1], pT[0] + pT[1], qT[0] + qT[1], cr, sr);
                const v2f crv = {cr, cr}, srv = {sr, sr}, nsv = {-sr, -sr};
                // always-swap: pos 2s <- v' = cr*Y + sr*X ; pos 2s+1 <- u' = cr*X - sr*Y
                #pragma unroll
                for (int k = 0; k < 16; ++k) {
                    const v2f xo = X[k];
                    X[k] = pk_fma(crv, Y[k], pk_mul(srv, xo));   // cr*Y + sr*xo
                    Y[k] = pk_fma(nsv, Y[k], pk_mul(crv, xo));   // cr*xo - sr*Y
                }
            }
            // ---------- odd round: pair (u = Y_s @ pos 2s+1, v = X_{s+1} @ pos 2s+2)
            {
                v2f o2[16];                 // partner column, fetched ONCE, carried
                v2f dA={0,0}, dB={0,0}, pA={0,0}, pB={0,0}, qA={0,0}, qB={0,0};
                #pragma unroll
                for (int k = 0; k < 16; ++k) {
                    v2f o;
                    o[0] = dpp_next0(X[k][0]);
                    o[1] = dpp_next0(X[k][1]);
                    o2[k] = o;
                    if (k & 1) { pk_acc(dB, Y[k], o); pk_acc(qB, o, o);
                                 pk_acc(pB, Y[k], Y[k]); }
                    else       { pk_acc(dA, Y[k], o); pk_acc(qA, o, o);
                                 pk_acc(pA, Y[k], Y[k]); }
                }
                v2f dT = dA + dB, pT = pA + pB, qT = qA + qB;
                float cr, sr;
                make_rot(dT[0] + dT[1], pT[0] + pT[1], qT[0] + qT[1], cr, sr);
                // boundary: position 31 (tail lane's Y) is unpaired -> (cr,sr)=(0,1)
                // makes Y' = Y exactly; its shipped u' dies at the row boundary.
                cr = tail ? 0.f : cr;
                sr = tail ? 1.f : sr;
                const v2f crv = {cr, cr}, srv = {sr, sr}, nsv = {-sr, -sr};
                #pragma unroll
                for (int k = 0; k < 16; ++k) {
                    const v2f o  = o2[k];
                    const v2f yo = Y[k];
                    Y[k]  = pk_fma(crv, o,  pk_mul(srv, yo));  // v' = cr*o + sr*yo
                    v2f u = pk_fma(crv, yo, pk_mul(nsv, o));   // u' = cr*yo - sr*o
                    X[k][0] = dpp_ship(X[k][0], u[0]);   // lane 0 keeps X (pos 0 idle)
                    X[k][1] = dpp_ship(X[k][1], u[1]);
                }
            }
        }
    }

    // ---------- epilogue: sigma, log, normalize; X = sum_c l_c u_c u_c^T ----------
    float nx2, ny2;
    {
        v2f a={0,0}, b={0,0};
        #pragma unroll
        for (int k = 0; k < 16; k += 2) { pk_acc(a, X[k], X[k]); pk_acc(b, X[k+1], X[k+1]); }
        v2f t = a + b; nx2 = t[0] + t[1];
    }
    {
        v2f a={0,0}, b={0,0};
        #pragma unroll
        for (int k = 0; k < 16; k += 2) { pk_acc(a, Y[k], Y[k]); pk_acc(b, Y[k+1], Y[k+1]); }
        v2f t = a + b; ny2 = t[0] + t[1];
    }
    const float invx = __builtin_amdgcn_rsqf(nx2);               // 1/sigma
    const float invy = __builtin_amdgcn_rsqf(ny2);
    const float lgx  = 0.34657359f * __builtin_amdgcn_logf(nx2); // ln(sigma)
    const float lgy  = 0.34657359f * __builtin_amdgcn_logf(ny2);

    // Per-wave LDS slice; one matrix per phase. 4 x 32 x 36 x 4B = 18432 B;
    // at 4 blocks/CU = 73.7 KB <= 160 KB -> LDS never binds.
    // Row stride 36 keeps 16-float halves 16B-aligned; log(eig) in pad [c][33].
    __shared__ __align__(16) float S[4][32][36];

    const int r = lane >> 1;       // output row this lane accumulates
    const int h = lane & 1;        // which 16-float half of that row

    #pragma unroll 1
    for (int ph = 0; ph < 4; ++ph) {
        __syncthreads();           // protect S reuse across phases (uniform count)
        if (mg == ph) {
            #pragma unroll
            for (int k = 0; k < 16; ++k) {
                *reinterpret_cast<v2f*>(&S[wv][2*sub][2*k])   = X[k] * invx;
                *reinterpret_cast<v2f*>(&S[wv][2*sub+1][2*k]) = Y[k] * invy;
            }
            S[wv][2*sub][33]   = lgx;
            S[wv][2*sub+1][33] = lgy;
        }
        __syncthreads();

        // All 64 lanes of the wave cooperate on its matrix `ph`.
        v2f acc[8];
        #pragma unroll
        for (int j = 0; j < 8; ++j) acc[j] = (v2f){0.f, 0.f};
        #pragma unroll 4
        for (int c = 0; c < 32; ++c) {
            const float m = S[wv][c][r] * S[wv][c][33];   // u_c[r] * log(lambda_c)
            const v2f mv = {m, m};
            const float4* row4 = reinterpret_cast<const float4*>(&S[wv][c][h * 16]);
            #pragma unroll
            for (int j4 = 0; j4 < 4; ++j4) {
                float4 v = row4[j4];
                pk_acc(acc[2*j4],   mv, (v2f){v.x, v.y});
                pk_acc(acc[2*j4+1], mv, (v2f){v.z, v.w});
            }
        }
        int m2 = blockIdx.x * 16 + wv * 4 + ph;
        if (m2 >= nmat) m2 = nmat - 1;
        // lane -> (r,h): consecutive lanes write consecutive 16B -> fully coalesced.
        float4* d4 = reinterpret_cast<float4*>(out + (size_t)m2 * 1024 +
                                               (size_t)r * 32 + h * 16);
        #pragma unroll
        for (int j4 = 0; j4 < 4; ++j4)
            d4[j4] = make_float4(acc[2*j4][0], acc[2*j4][1],
                                 acc[2*j4+1][0], acc[2*j4+1][1]);
    }
}

extern "C" void kernel_launch(void* const* d_in, const int* in_sizes, int n_in,
                              void* d_out, int out_size, void* d_ws, size_t ws_size,
                              hipStream_t stream) {
    const float* P = (const float*)d_in[0];
    float* out = (float*)d_out;
    const int nmat = in_sizes[0] / 1024;     // 32768
    const int nblocks = (nmat + 15) / 16;    // 16 matrices per 256-thread block
    logeig_kernel<<<nblocks, 256, 0, stream>>>(P, out, nmat);
}